// Round 8
// baseline (17.424 us; speedup 1.0000x reference)
//
#include <hip/hip_runtime.h>
#include <hip/hip_fp16.h>
#include <stdint.h>

// out[8,8192] = x[8,8192] @ W.T, W[n,k] = nibble(Qidxs[n,k/8], INV[k%8]) - 7.5
// R8: MLP fix. B staged via async global_load_lds (8 x dwordx4 per wave, no VGPR
// destinations -> ~128KB/CU in flight), XOR-swizzled source + swizzled ds_read_b32
// (linear LDS dest requirement, G21). Rest = R7 structure:
//   kernel 1: A-frag table [256 steps][33 slots][16B] in d_ws (slot 32 = zeros).
//   kernel 2: 512 blocks (16 n-rows) x 512 threads (8 waves; wave owns 1024 K,
//   32 x mfma_f32_16x16x32_f16, 1 swizzled ds_read_b32 + ~15 VALU per step).
//   End: one barrier + 8-way LDS reduce + coalesced store. 69632 B LDS -> 2 blk/CU.

typedef _Float16 half8 __attribute__((ext_vector_type(8)));
typedef float floatx4 __attribute__((ext_vector_type(4)));

union H2U { unsigned u; __half2 h; };
union V4H8 { uint4 u4; half8 h8; };

// nibbles {b, b+4} of w -> f16 pair {n_b, n_{b+4}} - 7.5, exact
__device__ __forceinline__ unsigned unpack_even(unsigned w, __half2 c1, __half2 c2) {
    H2U t; t.u = (w & 0x000F000Fu) | 0x64006400u;      // 1024 + n
    t.h = __hadd2(__hadd2(t.h, c1), c2);               // -1024, -7.5
    return t.u;
}
__device__ __forceinline__ unsigned unpack_odd(unsigned w, __half2 cs, __half2 cc) {
    H2U t; t.u = (w & 0x00F000F0u) | 0x64006400u;      // 1024 + 16n
    t.h = __hfma2(t.h, cs, cc);                        // /16, -71.5
    return t.u;
}

__device__ __forceinline__ void gload_lds16(const void* g, void* l) {
    __builtin_amdgcn_global_load_lds(
        (const __attribute__((address_space(1))) unsigned*)g,
        (__attribute__((address_space(3))) unsigned*)l, 16, 0, 0);
}

#define TPITCH 528                  // 33 slots x 16B per A-table step
#define NWV    8
#define BWAVE  8192                 // 16 rows x 512B, linear (global_load_lds dest)
#define REDOFF (NWV * BWAVE)        // 65536
#define LDS_BYTES (REDOFF + NWV * 128 * 4)   // 69632 -> 2 blocks/CU

// ---- kernel 1: A-frag table, one block per K-step ----
__global__ void build_atable(const float* __restrict__ x, char* __restrict__ tbl)
{
    const int S = blockIdx.x;           // 0..255, k-base = 32*S
    const int t = threadIdx.x;          // 0..63; 0..32 active
    if (t > 32) return;
    uint4 v = make_uint4(0u, 0u, 0u, 0u);
    if (t < 32) {
        const int u = t >> 3, r = t & 7;            // slot = 8u + r = t
        const float4* x4 = (const float4*)x;        // 2048 float4 per b-row
        float4 fa = x4[r * 2048 + 8 * S + 2 * u];       // cols 32S+8u+0..3
        float4 fb = x4[r * 2048 + 8 * S + 2 * u + 1];   // cols 32S+8u+4..7
        H2U a0, a1, a2, a3;
        a0.h = __floats2half2_rn(fa.x, fa.y);
        a1.h = __floats2half2_rn(fa.z, fa.w);
        a2.h = __floats2half2_rn(fb.x, fb.y);
        a3.h = __floats2half2_rn(fb.z, fb.w);
        v = make_uint4(a0.u, a1.u, a2.u, a3.u);
    }
    const int slot = (t < 32) ? t : 32;             // slot 32 = zeros (pad rows)
    *(uint4*)(tbl + S * TPITCH + slot * 16) = v;
}

__global__ __launch_bounds__(512, 4)
void hi4b_gemm(const char* __restrict__ atbl, const int* __restrict__ q,
               float* __restrict__ out)
{
    extern __shared__ char lds[];
    const int tid  = threadIdx.x;
    const int lane = tid & 63;
    const int wv   = tid >> 6;            // 0..7: K-window wv*1024
    const int n0   = blockIdx.x * 16;

    const int r16 = lane & 15;            // n (B) / C col
    const int u4  = lane >> 4;            // kgroup

    // ---- stage B async: 16 rows x 512B, source pre-swizzled (G21) ----
    // LDS dest is linear: inst j writes bytes [j*1024, j*1024+1024) = rows 2j,2j+1.
    // LDS chunk (row, c) receives global chunk (row, c ^ (row&7)).
    {
        const int uu = lane >> 5, cc = lane & 31;   // row-half, 16B chunk
        const char* gq = (const char*)q;            // Q row = 4096 B
        char* ldst = lds + wv * BWAVE;
        #pragma unroll
        for (int j = 0; j < 8; ++j) {
            const int row = 2 * j + uu;
            const char* src = gq + (size_t)(n0 + row) * 4096 + wv * 512
                            + ((cc ^ (row & 7)) << 4);
            gload_lds16(src, ldst + j * 1024);
        }
    }
    __builtin_amdgcn_sched_barrier(0);

    // ---- A: direct global from table, 4-step tiles, 2 in flight ----
    const int  slot = (r16 < 8) ? (u4 * 8 + r16) : 32;
    const char* ap  = atbl + (wv * 32) * TPITCH + slot * 16;

    uint4 T0[4], T1[4];
    auto refill = [&](uint4 (&T)[4], int t) {
        const char* p = ap + t * (4 * TPITCH);
        #pragma unroll
        for (int i = 0; i < 4; ++i)
            T[i] = *(const uint4*)(p + i * TPITCH);
    };
    refill(T0, 0);
    refill(T1, 1);

    // B (and T0/T1) guaranteed in LDS/regs past this point
    asm volatile("s_waitcnt vmcnt(0)" ::: "memory");
    __builtin_amdgcn_sched_barrier(0);

    const __half2 c1 = __floats2half2_rn(-1024.0f, -1024.0f);
    const __half2 c2 = __floats2half2_rn(-7.5f, -7.5f);
    const __half2 cs = __floats2half2_rn(0.0625f, 0.0625f);
    const __half2 cc = __floats2half2_rn(-71.5f, -71.5f);

    floatx4 acc = {0.0f, 0.0f, 0.0f, 0.0f};
    // step s: G word (row r16, 4s+u4) lives at LDS chunk s^(r16&7), word u4
    const char* bp = lds + wv * BWAVE + r16 * 512 + u4 * 4;
    const int sx = (r16 & 7) << 4;

    auto comp4 = [&](uint4 (&T)[4], int t) {
        #pragma unroll
        for (int i = 0; i < 4; ++i) {
            const int s = 4 * t + i;
            unsigned w  = *(const unsigned*)(bp + (((s << 4)) ^ sx));
            unsigned w8 = w >> 8;
            V4H8 Bf;
            Bf.u4.x = unpack_even(w,  c1, c2);   // cols +0,+1 (nib 0,4)
            Bf.u4.y = unpack_odd (w,  cs, cc);   // cols +2,+3 (nib 1,5)
            Bf.u4.z = unpack_even(w8, c1, c2);   // cols +4,+5 (nib 2,6)
            Bf.u4.w = unpack_odd (w8, cs, cc);   // cols +6,+7 (nib 3,7)
            V4H8 A;  A.u4 = T[i];
            acc = __builtin_amdgcn_mfma_f32_16x16x32_f16(A.h8, Bf.h8, acc, 0, 0, 0);
        }
    };

    // 8 tiles of 4 steps; A 2 tiles ahead, named buffers
    comp4(T0, 0); refill(T0, 2);
    comp4(T1, 1); refill(T1, 3);
    comp4(T0, 2); refill(T0, 4);
    comp4(T1, 3); refill(T1, 5);
    comp4(T0, 4); refill(T0, 6);
    comp4(T1, 5); refill(T1, 7);
    comp4(T0, 6);
    comp4(T1, 7);

    // ---- cross-wave reduce: C row = 4*u4 + reg (= b), col = r16 ----
    {
        float* red = (float*)(lds + REDOFF) + wv * 128;
        if (u4 < 2) {
            #pragma unroll
            for (int r = 0; r < 4; ++r)
                red[(u4 * 4 + r) * 16 + r16] = acc[r];
        }
    }
    __syncthreads();
    if (tid < 128) {
        const float* rd = (const float*)(lds + REDOFF);
        float sm = 0.0f;
        #pragma unroll
        for (int w = 0; w < NWV; ++w)
            sm += rd[w * 128 + tid];
        out[(tid >> 4) * 8192 + n0 + (tid & 15)] = sm;
    }
}

extern "C" void kernel_launch(void* const* d_in, const int* in_sizes, int n_in,
                              void* d_out, int out_size, void* d_ws, size_t ws_size,
                              hipStream_t stream)
{
    const float* x = (const float*)d_in[0];
    const int*   q = (const int*)d_in[1];
    float* out = (float*)d_out;
    char*  tbl = (char*)d_ws;              // 256*528 = 135168 B

    hipLaunchKernelGGL(build_atable, dim3(256), dim3(64), 0, stream, x, tbl);
    hipLaunchKernelGGL(hi4b_gemm, dim3(512), dim3(512), LDS_BYTES, stream,
                       tbl, q, out);
}